// Round 2
// baseline (638.767 us; speedup 1.0000x reference)
//
#include <hip/hip_runtime.h>

#define H_DIM 768
#define C_DIM 512
#define L_DIM 256
#define S_DIM 2048
#define B_DIM 16

typedef __attribute__((ext_vector_type(8))) short short8;
typedef __attribute__((ext_vector_type(4))) float f32x4;
typedef __attribute__((ext_vector_type(4))) unsigned short ushort4v;

#define MFMA_F16(a, b, c) __builtin_amdgcn_mfma_f32_16x16x32_f16((a), (b), (c), 0, 0, 0)

__device__ __forceinline__ unsigned short f2h(float f) {
    _Float16 h = (_Float16)f;
    return __builtin_bit_cast(unsigned short, h);
}
__device__ __forceinline__ float sigmoid_f(float x) { return 1.0f / (1.0f + __expf(-x)); }

// load 8 consecutive f32 and convert to 8 packed f16 (one MFMA frag)
__device__ __forceinline__ short8 cvt8(const float* p) {
    const float4* q = (const float4*)(const void*)p;
    float4 u = q[0], v = q[1];
    short8 r;
    r[0] = (short)f2h(u.x); r[1] = (short)f2h(u.y); r[2] = (short)f2h(u.z); r[3] = (short)f2h(u.w);
    r[4] = (short)f2h(v.x); r[5] = (short)f2h(v.y); r[6] = (short)f2h(v.z); r[7] = (short)f2h(v.w);
    return r;
}

// ---------------------------------------------------------------------------
// Kernel 0: convert Wi, Wia (f32 [C][H]) to f16 once. 4 elems/thread.
// ---------------------------------------------------------------------------
__global__ __launch_bounds__(256) void prep_weights(
    const float* __restrict__ Wi, const float* __restrict__ Wia,
    unsigned short* __restrict__ Wi_h, unsigned short* __restrict__ Wia_h)
{
    const int i = blockIdx.x * 256 + threadIdx.x;   // over (512*768)/4
    float4 a = ((const float4*)Wi)[i];
    float4 b = ((const float4*)Wia)[i];
    ushort4v ah = { f2h(a.x), f2h(a.y), f2h(a.z), f2h(a.w) };
    ushort4v bh = { f2h(b.x), f2h(b.y), f2h(b.z), f2h(b.w) };
    ((ushort4v*)Wi_h)[i]  = ah;
    ((ushort4v*)Wia_h)[i] = bh;
}

// ---------------------------------------------------------------------------
// Kernel 1: label-side GEMMs (f32 in, f16 out).
//   lt_t[c*256 + l]   = f16( sigmoid(lab[l]·Wl[c] + bl[c]) )          (transposed)
//   la_ctx[l*512 + c] = f16( sigmoid(lab[l]·Wla[c] + bla[c]) * ctx[c] )
// ---------------------------------------------------------------------------
__global__ __launch_bounds__(256) void label_kernel(
    const float* __restrict__ lab,
    const float* __restrict__ Wl,  const float* __restrict__ bl,
    const float* __restrict__ Wla, const float* __restrict__ bla,
    const float* __restrict__ context,
    unsigned short* __restrict__ lt_t,
    unsigned short* __restrict__ la_ctx)
{
    __shared__ float labrow[H_DIM];
    const int l = blockIdx.x;
    const int t = threadIdx.x;
    for (int i = t; i < H_DIM; i += 256) labrow[i] = lab[l * H_DIM + i];
    __syncthreads();
    for (int c = t; c < C_DIM; c += 256) {
        const float4* wl  = (const float4*)(const void*)(Wl  + c * H_DIM);
        const float4* wla = (const float4*)(const void*)(Wla + c * H_DIM);
        float s1 = 0.f, s2 = 0.f;
        for (int k4 = 0; k4 < H_DIM / 4; ++k4) {
            float4 w1 = wl[k4], w2 = wla[k4];
            const float* lr = &labrow[k4 * 4];
            s1 += lr[0] * w1.x + lr[1] * w1.y + lr[2] * w1.z + lr[3] * w1.w;
            s2 += lr[0] * w2.x + lr[1] * w2.y + lr[2] * w2.z + lr[3] * w2.w;
        }
        lt_t[c * L_DIM + l]   = f2h(sigmoid_f(s1 + bl[c]));
        la_ctx[l * C_DIM + c] = f2h(sigmoid_f(s2 + bla[c]) * context[c]);
    }
}

// ---------------------------------------------------------------------------
// Kernel 2: fused main. One block = 32 rows of [B*S]. 4 waves, C/L-split.
// Phase1: joint ia+it GEMM over x (shared A-frags). ia -> LDS -> logits ->
// softmax(unnorm, keep 1/sum) -> attn(f16, LDS) -> weighted -> fusion atomics.
// MFMA 16x16x32: A frag = A[m=lane&15][k=quad*8+j], B frag = B[n=lane&15][k],
// C/D: col = lane&15, row = quad*4 + reg  (verified layouts, m89/m91).
// ---------------------------------------------------------------------------
__global__ __launch_bounds__(256) void fused_main(
    const float* __restrict__ x,
    const float* __restrict__ bi,
    const float* __restrict__ bia,
    const unsigned short* __restrict__ Wi_h,    // f16 [C][H]
    const unsigned short* __restrict__ Wia_h,   // f16 [C][H]
    const unsigned short* __restrict__ lt_t,    // f16 [C][L]
    const unsigned short* __restrict__ la_ctx,  // f16 [L][C]
    float* __restrict__ fusion)                 // f32 [B][C]
{
    __shared__ unsigned short lds_buf[32 * C_DIM]; // ia f16 [32][512]; first half reused as attn [32][256]
    __shared__ float rowscratch[4 * 32];
    __shared__ float inv_lds[32];

    const int tid  = threadIdx.x;
    const int wave = tid >> 6;
    const int lane = tid & 63;
    const int quad = lane >> 4;
    const int c16  = lane & 15;

    const int row0 = blockIdx.x * 32;
    const int b    = row0 >> 11;   // / 2048

    const f32x4 z4 = {0.f, 0.f, 0.f, 0.f};
    const int n0 = wave * 128;     // C-column split for ia / it / weighted

    // ========== Phase 1: joint GEMM  ia = x@Wia^T, it = x@Wi^T (K=768) ====
    f32x4 acc[2][8], acci[2][8];
#pragma unroll
    for (int mt = 0; mt < 2; ++mt)
#pragma unroll
        for (int nt = 0; nt < 8; ++nt) { acc[mt][nt] = z4; acci[mt][nt] = z4; }
    {
        const float* xb = x + (size_t)(row0 + c16) * H_DIM + quad * 8;
        const unsigned short* wa = Wia_h + (size_t)(n0 + c16) * H_DIM + quad * 8;
        const unsigned short* wi = Wi_h  + (size_t)(n0 + c16) * H_DIM + quad * 8;
        for (int kk = 0; kk < H_DIM; kk += 32) {
            short8 a0 = cvt8(xb + kk);
            short8 a1 = cvt8(xb + 16 * H_DIM + kk);
#pragma unroll
            for (int nt = 0; nt < 8; ++nt) {
                short8 ba = *(const short8*)(const void*)(wa + nt * 16 * H_DIM + kk);
                short8 bw = *(const short8*)(const void*)(wi + nt * 16 * H_DIM + kk);
                acc[0][nt]  = MFMA_F16(a0, ba, acc[0][nt]);
                acc[1][nt]  = MFMA_F16(a1, ba, acc[1][nt]);
                acci[0][nt] = MFMA_F16(a0, bw, acci[0][nt]);
                acci[1][nt] = MFMA_F16(a1, bw, acci[1][nt]);
            }
        }
    }
    // sigmoid(ia + bia) -> LDS f16 [32][512]
#pragma unroll
    for (int nt = 0; nt < 8; ++nt) {
        const int col = n0 + nt * 16 + c16;
        const float bv = bia[col];
#pragma unroll
        for (int mt = 0; mt < 2; ++mt)
#pragma unroll
            for (int r = 0; r < 4; ++r) {
                const int row = mt * 16 + quad * 4 + r;
                lds_buf[row * C_DIM + col] = f2h(sigmoid_f(acc[mt][nt][r] + bv));
            }
    }
    __syncthreads();

    // ========== Phase 2: logits = ia @ la_ctx^T (K=512) ===================
    const int n0l = wave * 64;   // L-column split
    f32x4 accl[2][4];
#pragma unroll
    for (int mt = 0; mt < 2; ++mt)
#pragma unroll
        for (int nt = 0; nt < 4; ++nt) accl[mt][nt] = z4;
    {
        const unsigned short* ab = lds_buf + c16 * C_DIM + quad * 8;
        const unsigned short* bb = la_ctx + (size_t)(n0l + c16) * C_DIM + quad * 8;
        for (int kk = 0; kk < C_DIM; kk += 32) {
            short8 a0 = *(const short8*)(const void*)(ab + kk);
            short8 a1 = *(const short8*)(const void*)(ab + 16 * C_DIM + kk);
#pragma unroll
            for (int nt = 0; nt < 4; ++nt) {
                short8 bfr = *(const short8*)(const void*)(bb + nt * 16 * C_DIM + kk);
                accl[0][nt] = MFMA_F16(a0, bfr, accl[0][nt]);
                accl[1][nt] = MFMA_F16(a1, bfr, accl[1][nt]);
            }
        }
    }
    __syncthreads();   // all ia reads complete; lds_buf reusable

    // ========== Phase 3: softmax over L (unnormalized; keep 1/sum) ========
    float rmax[2][4];
#pragma unroll
    for (int mt = 0; mt < 2; ++mt)
#pragma unroll
        for (int r = 0; r < 4; ++r) {
            float m = accl[mt][0][r];
#pragma unroll
            for (int nt = 1; nt < 4; ++nt) m = fmaxf(m, accl[mt][nt][r]);
#pragma unroll
            for (int off = 1; off < 16; off <<= 1) m = fmaxf(m, __shfl_xor(m, off, 64));
            rmax[mt][r] = m;
        }
    if (c16 == 0) {
#pragma unroll
        for (int mt = 0; mt < 2; ++mt)
#pragma unroll
            for (int r = 0; r < 4; ++r)
                rowscratch[wave * 32 + mt * 16 + quad * 4 + r] = rmax[mt][r];
    }
    __syncthreads();
    float rsum[2][4];
#pragma unroll
    for (int mt = 0; mt < 2; ++mt)
#pragma unroll
        for (int r = 0; r < 4; ++r) {
            const int row = mt * 16 + quad * 4 + r;
            float gm = rowscratch[row];
#pragma unroll
            for (int w = 1; w < 4; ++w) gm = fmaxf(gm, rowscratch[w * 32 + row]);
            float s = 0.f;
#pragma unroll
            for (int nt = 0; nt < 4; ++nt) {
                float e = __expf(accl[mt][nt][r] - gm);
                accl[mt][nt][r] = e;
                s += e;
            }
#pragma unroll
            for (int off = 1; off < 16; off <<= 1) s += __shfl_xor(s, off, 64);
            rsum[mt][r] = s;
        }
    __syncthreads();   // maxima consumed
    if (c16 == 0) {
#pragma unroll
        for (int mt = 0; mt < 2; ++mt)
#pragma unroll
            for (int r = 0; r < 4; ++r)
                rowscratch[wave * 32 + mt * 16 + quad * 4 + r] = rsum[mt][r];
    }
    __syncthreads();
#pragma unroll
    for (int mt = 0; mt < 2; ++mt)
#pragma unroll
        for (int r = 0; r < 4; ++r) {
            const int row = mt * 16 + quad * 4 + r;
            const float st = rowscratch[row] + rowscratch[32 + row]
                           + rowscratch[64 + row] + rowscratch[96 + row];
            if (wave == 0 && c16 == 0) inv_lds[row] = 1.0f / st;
            // unnormalized attn e-values, f16, row-major [32][256]
#pragma unroll
            for (int nt = 0; nt < 4; ++nt)
                lds_buf[row * L_DIM + n0l + nt * 16 + c16] = f2h(accl[mt][nt][r]);
        }
    __syncthreads();

    // ========== Phase 4: weighted = attn @ lt (via lt_t), K=256 ===========
    f32x4 accw[2][8];
#pragma unroll
    for (int mt = 0; mt < 2; ++mt)
#pragma unroll
        for (int nt = 0; nt < 8; ++nt) accw[mt][nt] = z4;
    {
        const unsigned short* ab = lds_buf + c16 * L_DIM + quad * 8;
        const unsigned short* bb = lt_t + (size_t)(n0 + c16) * L_DIM + quad * 8;
        for (int kk = 0; kk < L_DIM; kk += 32) {
            short8 a0 = *(const short8*)(const void*)(ab + kk);
            short8 a1 = *(const short8*)(const void*)(ab + 16 * L_DIM + kk);
#pragma unroll
            for (int nt = 0; nt < 8; ++nt) {
                short8 bfr = *(const short8*)(const void*)(bb + nt * 16 * L_DIM + kk);
                accw[0][nt] = MFMA_F16(a0, bfr, accw[0][nt]);
                accw[1][nt] = MFMA_F16(a1, bfr, accw[1][nt]);
            }
        }
    }

    // ========== Phase 5: fusion[b][c] += sum_rows it * weighted * invsum ==
    float invr[2][4];
#pragma unroll
    for (int mt = 0; mt < 2; ++mt)
#pragma unroll
        for (int r = 0; r < 4; ++r) invr[mt][r] = inv_lds[mt * 16 + quad * 4 + r];
#pragma unroll
    for (int nt = 0; nt < 8; ++nt) {
        const int col = n0 + nt * 16 + c16;
        const float bv = bi[col];
        float s = 0.f;
#pragma unroll
        for (int mt = 0; mt < 2; ++mt)
#pragma unroll
            for (int r = 0; r < 4; ++r)
                s += accw[mt][nt][r] * sigmoid_f(acci[mt][nt][r] + bv) * invr[mt][r];
        s += __shfl_xor(s, 16, 64);
        s += __shfl_xor(s, 32, 64);
        if (lane < 16) atomicAdd(&fusion[b * C_DIM + col], s);
    }
}

// ---------------------------------------------------------------------------
// Kernel 3: out[b][h] = sum_c fusion[b][c] * Wp[h][c]   (f32 out)
// ---------------------------------------------------------------------------
__global__ __launch_bounds__(256) void out_kernel(
    const float* __restrict__ fusion,
    const float* __restrict__ Wp,
    float* __restrict__ out)
{
    const int idx = blockIdx.x * 256 + threadIdx.x;
    const int bb = idx / H_DIM;
    const int h  = idx - bb * H_DIM;
    const float4* wp = (const float4*)(const void*)(Wp + h * C_DIM);
    const float* f = fusion + bb * C_DIM;
    float s = 0.f;
    for (int k4 = 0; k4 < C_DIM / 4; ++k4) {
        float4 wv = wp[k4];
        s += f[k4 * 4 + 0] * wv.x + f[k4 * 4 + 1] * wv.y
           + f[k4 * 4 + 2] * wv.z + f[k4 * 4 + 3] * wv.w;
    }
    out[idx] = s;
}

extern "C" void kernel_launch(void* const* d_in, const int* in_sizes, int n_in,
                              void* d_out, int out_size, void* d_ws, size_t ws_size,
                              hipStream_t stream)
{
    const float* x    = (const float*)d_in[0];
    const float* lab  = (const float*)d_in[1];
    const float* Wi   = (const float*)d_in[2];
    const float* bi   = (const float*)d_in[3];
    const float* Wl   = (const float*)d_in[4];
    const float* bl   = (const float*)d_in[5];
    const float* Wia  = (const float*)d_in[6];
    const float* bia  = (const float*)d_in[7];
    const float* Wla  = (const float*)d_in[8];
    const float* bla  = (const float*)d_in[9];
    const float* ctx  = (const float*)d_in[10];
    const float* Wp   = (const float*)d_in[11];

    char* ws = (char*)d_ws;
    unsigned short* lt_t   = (unsigned short*)(ws);              // f16 [512][256] = 256 KB
    unsigned short* la_ctx = (unsigned short*)(ws + 262144);     // f16 [256][512] = 256 KB
    unsigned short* Wi_h   = (unsigned short*)(ws + 524288);     // f16 [512][768] = 768 KB
    unsigned short* Wia_h  = (unsigned short*)(ws + 1310720);    // f16 [512][768] = 768 KB
    float* fusion          = (float*)(ws + 2097152);             // f32 [16][512]  =  32 KB

    hipMemsetAsync(fusion, 0, B_DIM * C_DIM * sizeof(float), stream);
    prep_weights<<<(C_DIM * H_DIM) / (4 * 256), 256, 0, stream>>>(Wi, Wia, Wi_h, Wia_h);
    label_kernel<<<L_DIM, 256, 0, stream>>>(lab, Wl, bl, Wla, bla, ctx, lt_t, la_ctx);
    fused_main<<<(B_DIM * S_DIM) / 32, 256, 0, stream>>>(x, bi, bia, Wi_h, Wia_h, lt_t, la_ctx, fusion);
    out_kernel<<<(B_DIM * H_DIM) / 256, 256, 0, stream>>>(fusion, Wp, (float*)d_out);
}